// Round 3
// baseline (932.609 us; speedup 1.0000x reference)
//
#include <hip/hip_runtime.h>

#define NN 50000
#define NE 400000
#define DIN 32
#define DH  128
#define DOUT 16
#define NB  2

typedef _Float16 half8 __attribute__((ext_vector_type(8)));
typedef float    f32x4 __attribute__((ext_vector_type(4)));

// compile-order + LDS-completion fence (intra-wave cross-lane LDS reuse)
#define FENCE() asm volatile("s_waitcnt lgkmcnt(0)" ::: "memory")

// ---------------------------------------------------------------------------
// xa = f16(inputs @ win + bin)
__global__ void k_node_proj(const float* __restrict__ inp,
                            const float* __restrict__ win,
                            const float* __restrict__ bin,
                            _Float16* __restrict__ x16) {
    int gid = blockIdx.x * blockDim.x + threadIdx.x;
    if (gid >= NN * DH) return;
    int n = gid >> 7, h = gid & 127;
    float acc = bin[h];
    const float* row = inp + (size_t)n * DIN;
#pragma unroll
    for (int k = 0; k < DIN; ++k) acc = fmaf(row[k], win[k * DH + h], acc);
    x16[gid] = (_Float16)acc;
}

// ---------------------------------------------------------------------------
// Fragment-linear f16 weights. Per block: 24 t-tiles x 512 chunks of 8 f16.
// order: w1a(t0..7) w1b(4) w1c(4) w2a(4) w2b(4). chunk=(t*8+n)*64+l within
// matrix; elem j = W[t*32+(l>>4)*8+j][n*16+(l&15)].
__global__ void k_wprep(const float* __restrict__ w1a, const float* __restrict__ w1b,
                        const float* __restrict__ w1c, const float* __restrict__ w2a,
                        const float* __restrict__ w2b, _Float16* __restrict__ wf) {
    int c = blockIdx.x * blockDim.x + threadIdx.x;
    if (c >= NB * 12288) return;
    int b = c / 12288, r = c % 12288;
    int tt = r >> 9, rem = r & 511;
    const float* W; int t;
    if (tt < 8)       { W = w1a + (size_t)b * 2 * DH * DH; t = tt; }
    else if (tt < 12) { W = w1b + (size_t)b * DH * DH; t = tt - 8; }
    else if (tt < 16) { W = w1c + (size_t)b * DH * DH; t = tt - 12; }
    else if (tt < 20) { W = w2a + (size_t)b * DH * DH; t = tt - 16; }
    else              { W = w2b + (size_t)b * DH * DH; t = tt - 20; }
    int n = rem >> 6, l = rem & 63;
    int row0 = t * 32 + (l >> 4) * 8, col = n * 16 + (l & 15);
    half8 v;
#pragma unroll
    for (int j = 0; j < 8; ++j) v[j] = (_Float16)W[(size_t)(row0 + j) * DH + col];
    *(half8*)(wf + (size_t)c * 8) = v;
}

// ---------------------------------------------------------------------------
// CSR build: histogram -> scan -> scatter (sorted-by-dst edge arrays)
__global__ void k_hist(const int* __restrict__ dstI, int* __restrict__ deg) {
    int e = blockIdx.x * blockDim.x + threadIdx.x;
    if (e < NE) atomicAdd(&deg[dstI[e]], 1);
}

__global__ void __launch_bounds__(1024) k_scan(const int* __restrict__ deg,
                                               int* __restrict__ rowptr,
                                               int* __restrict__ cur) {
    __shared__ int wsum[16];
    __shared__ int carryS;
    int tid = threadIdx.x, wv = tid >> 6, l = tid & 63;
    if (tid == 0) carryS = 0;
    __syncthreads();
    for (int c = 0; c < 49; ++c) {
        int i = c * 1024 + tid;
        int v = (i < NN) ? deg[i] : 0;
        int s = v;
#pragma unroll
        for (int off = 1; off < 64; off <<= 1) {
            int t = __shfl_up(s, off);
            if (l >= off) s += t;
        }
        if (l == 63) wsum[wv] = s;
        __syncthreads();
        if (wv == 0) {
            int t = (l < 16) ? wsum[l] : 0;
#pragma unroll
            for (int off = 1; off < 16; off <<= 1) {
                int u = __shfl_up(t, off);
                if (l >= off) t += u;
            }
            if (l < 16) wsum[l] = t;
        }
        __syncthreads();
        int base = carryS + (wv ? wsum[wv - 1] : 0);
        int excl = base + s - v;
        if (i < NN) { rowptr[i] = excl; cur[i] = excl; }
        __syncthreads();
        if (tid == 0) carryS += wsum[15];
        __syncthreads();
    }
    if (threadIdx.x == 0) rowptr[NN] = carryS;
}

__global__ void k_scatter(const int* __restrict__ srcI, const int* __restrict__ dstI,
                          int* __restrict__ cur, int* __restrict__ eS,
                          int* __restrict__ eD) {
    int e = blockIdx.x * blockDim.x + threadIdx.x;
    if (e >= NE) return;
    int d = dstI[e];
    int p = atomicAdd(&cur[d], 1);
    eS[p] = srcI[e];
    eD[p] = d;
}

// ---------------------------------------------------------------------------
// epilogue: acc tile -> fragment-layout f16 in LDS (verified mapping, round 2)
__device__ __forceinline__ void ep_store(_Float16* sm, int off, const f32x4* acc,
                                         const float* bias, int lm, int lk,
                                         bool relu) {
#pragma unroll
    for (int n = 0; n < 8; ++n) {
        int base = off + (((n >> 1) * 64 + ((n & 1) * 2 + (lm >> 3)) * 16 + lk * 4) * 8)
                   + (lm & 7);
#pragma unroll
        for (int j = 0; j < 4; ++j) {
            float v = acc[n][j] + bias[n];
            if (relu) v = fmaxf(v, 0.f);
            sm[base + j * 8] = (_Float16)v;
        }
    }
}

// ---------------------------------------------------------------------------
// Fused per-graph-block kernel. WG owns 32 dst nodes + all their in-edges
// (CSR-sorted). 4 waves; each wave processes 32-edge tiles (2 MFMA sub-tiles
// sharing each B-frag). Aggregation in LDS (ds_add, segmented quad-reduce).
// Then fused node MLP: xout[d] = relu(agg@w2a+b2a)@w2b+b2b.
__global__ void __launch_bounds__(256) k_fused(
    const _Float16* __restrict__ xin,
    const int* __restrict__ eS, const int* __restrict__ eD,
    const int* __restrict__ rowptr,
    const half8* __restrict__ wf,   // this block's 12288 chunks
    const float* __restrict__ b1a, const float* __restrict__ b1b,
    const float* __restrict__ b1c,
    const float* __restrict__ b2a, const float* __restrict__ b2b,
    _Float16* __restrict__ xout) {
    __shared__ float aggL[33][128];       // 32 dst slots + dump row 32
    __shared__ _Float16 sM[4][4096];      // per-wave m1/m2 frag buffer (32 edges)
    __shared__ _Float16 hbuf[2][2048];    // node-MLP hidden frags

    const int tid = threadIdx.x, wv = tid >> 6, l = tid & 63;
    const int lm = l & 15, lk = l >> 4;
    const int d0 = blockIdx.x * 32;
    const int rp0 = rowptr[d0];
    const int dEnd = (d0 + 32 < NN) ? d0 + 32 : NN;
    const int rp1 = rowptr[dEnd];

    for (int i = tid; i < 33 * 128; i += 256) ((float*)aggL)[i] = 0.f;

    float ba[8], bb[8], bc[8];
#pragma unroll
    for (int n = 0; n < 8; ++n) {
        ba[n] = b1a[n * 16 + lm];
        bb[n] = b1b[n * 16 + lm];
        bc[n] = b1c[n * 16 + lm];
    }
    __syncthreads();

    _Float16* sm = sM[wv];
    const f32x4 z = {0.f, 0.f, 0.f, 0.f};
    const int ntile = (rp1 - rp0 + 31) >> 5;

    for (int tile = wv; tile < ntile; tile += 4) {
        const int ebase = rp0 + tile * 32;
        const int e0 = ebase + lm, e1 = ebase + 16 + lm;
        const bool v0 = e0 < rp1, v1 = e1 < rp1;
        const int s0 = v0 ? eS[e0] : 0, s1 = v1 ? eS[e1] : 0;
        const int dd0 = v0 ? eD[e0] : 0, dd1 = v1 ? eD[e1] : 0;
        const int sl0 = v0 ? dd0 - d0 : 32;
        const int sl1 = v1 ? dd1 - d0 : 32;

        f32x4 acc0[8], acc1[8];
#pragma unroll
        for (int n = 0; n < 8; ++n) { acc0[n] = z; acc1[n] = z; }

        // ---- layer 1: K=256 ([x_j | x_i])
#pragma unroll
        for (int t = 0; t < 8; ++t) {
            const int n0 = (t < 4) ? s0 : dd0;
            const int n1 = (t < 4) ? s1 : dd1;
            half8 a0 = *(const half8*)(xin + (size_t)n0 * DH + (t & 3) * 32 + lk * 8);
            half8 a1 = *(const half8*)(xin + (size_t)n1 * DH + (t & 3) * 32 + lk * 8);
            const half8* wp = wf + (size_t)t * 512 + l;
#pragma unroll
            for (int n = 0; n < 8; ++n) {
                half8 w = wp[n * 64];
                acc0[n] = __builtin_amdgcn_mfma_f32_16x16x32_f16(a0, w, acc0[n], 0, 0, 0);
                acc1[n] = __builtin_amdgcn_mfma_f32_16x16x32_f16(a1, w, acc1[n], 0, 0, 0);
            }
        }
        ep_store(sm, 0, acc0, ba, lm, lk, true);
        ep_store(sm, 2048, acc1, ba, lm, lk, true);
        FENCE();

        // ---- layer 2: K=128
#pragma unroll
        for (int n = 0; n < 8; ++n) { acc0[n] = z; acc1[n] = z; }
#pragma unroll
        for (int t = 0; t < 4; ++t) {
            half8 a0 = *(const half8*)&sm[(t * 64 + l) * 8];
            half8 a1 = *(const half8*)&sm[2048 + (t * 64 + l) * 8];
            const half8* wp = wf + 4096 + (size_t)t * 512 + l;
#pragma unroll
            for (int n = 0; n < 8; ++n) {
                half8 w = wp[n * 64];
                acc0[n] = __builtin_amdgcn_mfma_f32_16x16x32_f16(a0, w, acc0[n], 0, 0, 0);
                acc1[n] = __builtin_amdgcn_mfma_f32_16x16x32_f16(a1, w, acc1[n], 0, 0, 0);
            }
        }
        FENCE();
        ep_store(sm, 0, acc0, bb, lm, lk, true);
        ep_store(sm, 2048, acc1, bb, lm, lk, true);
        FENCE();

        // ---- layer 3: K=128
#pragma unroll
        for (int n = 0; n < 8; ++n) { acc0[n] = z; acc1[n] = z; }
#pragma unroll
        for (int t = 0; t < 4; ++t) {
            half8 a0 = *(const half8*)&sm[(t * 64 + l) * 8];
            half8 a1 = *(const half8*)&sm[2048 + (t * 64 + l) * 8];
            const half8* wp = wf + 6144 + (size_t)t * 512 + l;
#pragma unroll
            for (int n = 0; n < 8; ++n) {
                half8 w = wp[n * 64];
                acc0[n] = __builtin_amdgcn_mfma_f32_16x16x32_f16(a0, w, acc0[n], 0, 0, 0);
                acc1[n] = __builtin_amdgcn_mfma_f32_16x16x32_f16(a1, w, acc1[n], 0, 0, 0);
            }
        }

        // ---- segmented quad-reduce -> LDS agg (sorted dst => runs)
        int qs0[4], qs1[4];
#pragma unroll
        for (int j = 0; j < 4; ++j) {
            qs0[j] = __shfl(sl0, lk * 4 + j);
            qs1[j] = __shfl(sl1, lk * 4 + j);
        }
#pragma unroll
        for (int n = 0; n < 8; ++n) {
            const int f = n * 16 + lm;
            {
                int cs = qs0[0];
                float s = acc0[n][0] + bc[n];
#pragma unroll
                for (int j = 1; j < 4; ++j) {
                    if (qs0[j] != cs) {
                        unsafeAtomicAdd(&aggL[cs][f], s);
                        cs = qs0[j]; s = 0.f;
                    }
                    s += acc0[n][j] + bc[n];
                }
                unsafeAtomicAdd(&aggL[cs][f], s);
            }
            {
                int cs = qs1[0];
                float s = acc1[n][0] + bc[n];
#pragma unroll
                for (int j = 1; j < 4; ++j) {
                    if (qs1[j] != cs) {
                        unsafeAtomicAdd(&aggL[cs][f], s);
                        cs = qs1[j]; s = 0.f;
                    }
                    s += acc1[n][j] + bc[n];
                }
                unsafeAtomicAdd(&aggL[cs][f], s);
            }
        }
    }
    __syncthreads();   // all waves' aggregation complete

    // ---- fused node MLP: wave (g,nh) computes rows g*16.., cols nh*64..
    const int g = wv >> 1, nh = wv & 1;
    float b2ar[4], b2br[4];
#pragma unroll
    for (int n = 0; n < 4; ++n) {
        b2ar[n] = b2a[nh * 64 + n * 16 + lm];
        b2br[n] = b2b[nh * 64 + n * 16 + lm];
    }
    f32x4 acc[4];
#pragma unroll
    for (int n = 0; n < 4; ++n) acc[n] = z;
#pragma unroll
    for (int t = 0; t < 4; ++t) {
        const float* ap = &aggL[g * 16 + lm][t * 32 + lk * 8];
        half8 a;
#pragma unroll
        for (int i = 0; i < 8; ++i) a[i] = (_Float16)ap[i];
        const half8* wp = wf + 8192 + (size_t)t * 512 + nh * 256 + l;
#pragma unroll
        for (int n = 0; n < 4; ++n)
            acc[n] = __builtin_amdgcn_mfma_f32_16x16x32_f16(a, wp[n * 64], acc[n], 0, 0, 0);
    }
    // h -> hbuf[g] in fragment layout (col c = nh*64+n*16+lm)
#pragma unroll
    for (int n = 0; n < 4; ++n) {
        int base = (((nh * 2 + (n >> 1)) * 64 + ((n & 1) * 2 + (lm >> 3)) * 16 + lk * 4) * 8)
                   + (lm & 7);
#pragma unroll
        for (int j = 0; j < 4; ++j)
            hbuf[g][base + j * 8] = (_Float16)fmaxf(acc[n][j] + b2ar[n], 0.f);
    }
    __syncthreads();

#pragma unroll
    for (int n = 0; n < 4; ++n) acc[n] = z;
#pragma unroll
    for (int t = 0; t < 4; ++t) {
        half8 a = *(const half8*)&hbuf[g][(t * 64 + l) * 8];
        const half8* wp = wf + 10240 + (size_t)t * 512 + nh * 256 + l;
#pragma unroll
        for (int n = 0; n < 4; ++n)
            acc[n] = __builtin_amdgcn_mfma_f32_16x16x32_f16(a, wp[n * 64], acc[n], 0, 0, 0);
    }
#pragma unroll
    for (int n = 0; n < 4; ++n) {
#pragma unroll
        for (int j = 0; j < 4; ++j) {
            int d = d0 + g * 16 + lk * 4 + j;
            if (d < NN)
                xout[(size_t)d * DH + nh * 64 + n * 16 + lm] =
                    (_Float16)(acc[n][j] + b2br[n]);
        }
    }
}

// ---------------------------------------------------------------------------
__global__ void k_out(const _Float16* __restrict__ x16,
                      const float* __restrict__ wout,
                      const float* __restrict__ bout,
                      float* __restrict__ out) {
    int gid = blockIdx.x * blockDim.x + threadIdx.x;
    if (gid >= NN * DOUT) return;
    int n = gid >> 4, o = gid & 15;
    float acc = bout[o];
    const _Float16* row = x16 + (size_t)n * DH;
#pragma unroll 8
    for (int k = 0; k < DH; ++k) acc = fmaf((float)row[k], wout[k * DOUT + o], acc);
    out[gid] = acc;
}

// ---------------------------------------------------------------------------
extern "C" void kernel_launch(void* const* d_in, const int* in_sizes, int n_in,
                              void* d_out, int out_size, void* d_ws, size_t ws_size,
                              hipStream_t stream) {
    const float* inputs = (const float*)d_in[0];
    const int* eidx = (const int*)d_in[2];
    const int* srcI = eidx;
    const int* dstI = eidx + NE;
    const float* win  = (const float*)d_in[3];
    const float* bin_ = (const float*)d_in[4];
    const float* wout = (const float*)d_in[5];
    const float* bout = (const float*)d_in[6];
    const float* w1a = (const float*)d_in[7];
    const float* b1a = (const float*)d_in[8];
    const float* w1b = (const float*)d_in[9];
    const float* b1b = (const float*)d_in[10];
    const float* w1c = (const float*)d_in[11];
    const float* b1c = (const float*)d_in[12];
    const float* w2a = (const float*)d_in[13];
    const float* b2a = (const float*)d_in[14];
    const float* w2b = (const float*)d_in[15];
    const float* b2b = (const float*)d_in[16];

    // ws layout (bytes, 256-aligned)
    char* p = (char*)d_ws;
    _Float16* xa = (_Float16*)p;                  p += (size_t)NN * DH * 2;       // 12.8MB
    _Float16* xb = (_Float16*)p;                  p += (size_t)NN * DH * 2;       // 12.8MB
    _Float16* wfAll = (_Float16*)p;               p += (size_t)NB * 12288 * 16;   // 393KB
    int* deg    = (int*)p;                        p += (size_t)NN * 4;
    int* rowptr = (int*)p;                        p += (size_t)(NN + 1) * 4 + 252;
    int* cur    = (int*)p;                        p += (size_t)NN * 4;
    int* eSrt   = (int*)p;                        p += (size_t)NE * 4;
    int* eDrt   = (int*)p;                        p += (size_t)NE * 4;
    float* out  = (float*)d_out;

    k_wprep<<<(NB * 12288 + 255) / 256, 256, 0, stream>>>(w1a, w1b, w1c, w2a, w2b, wfAll);
    k_node_proj<<<(NN * DH + 255) / 256, 256, 0, stream>>>(inputs, win, bin_, xa);

    hipMemsetAsync(deg, 0, (size_t)NN * 4, stream);
    k_hist<<<(NE + 255) / 256, 256, 0, stream>>>(dstI, deg);
    k_scan<<<1, 1024, 0, stream>>>(deg, rowptr, cur);
    k_scatter<<<(NE + 255) / 256, 256, 0, stream>>>(srcI, dstI, cur, eSrt, eDrt);

    const int NWG = (NN + 31) / 32;
    for (int b = 0; b < NB; ++b) {
        const _Float16* xi = (b & 1) ? xb : xa;
        _Float16*       xo = (b & 1) ? xa : xb;
        k_fused<<<NWG, 256, 0, stream>>>(
            xi, eSrt, eDrt, rowptr,
            (const half8*)(wfAll + (size_t)b * 12288 * 8),
            b1a + (size_t)b * DH, b1b + (size_t)b * DH, b1c + (size_t)b * DH,
            b2a + (size_t)b * DH, b2b + (size_t)b * DH,
            xo);
    }

    k_out<<<(NN * DOUT + 255) / 256, 256, 0, stream>>>(xa, wout, bout, out);
}

// Round 4
// 661.812 us; speedup vs baseline: 1.4092x; 1.4092x over previous
//
#include <hip/hip_runtime.h>

#define NN 50000
#define NE 400000
#define DIN 32
#define DH  128
#define DOUT 16
#define NB  2
#define NBLK 49   // ceil(NN/1024)

typedef _Float16 half8 __attribute__((ext_vector_type(8)));
typedef float    f32x4 __attribute__((ext_vector_type(4)));

#define FENCE() asm volatile("s_waitcnt lgkmcnt(0)" ::: "memory")

// ---------------------------------------------------------------------------
__global__ void k_node_proj(const float* __restrict__ inp,
                            const float* __restrict__ win,
                            const float* __restrict__ bin,
                            _Float16* __restrict__ x16) {
    int gid = blockIdx.x * blockDim.x + threadIdx.x;
    if (gid >= NN * DH) return;
    int n = gid >> 7, h = gid & 127;
    float acc = bin[h];
    const float* row = inp + (size_t)n * DIN;
#pragma unroll
    for (int k = 0; k < DIN; ++k) acc = fmaf(row[k], win[k * DH + h], acc);
    x16[gid] = (_Float16)acc;
}

// ---------------------------------------------------------------------------
// Fragment-linear f16 edge-MLP weights (verified round 2).
// Per block: 8192 chunks of 8 f16: w1a t0..7 | w1b t0..3 | w1c t0..3.
__global__ void k_wprep(const float* __restrict__ w1a, const float* __restrict__ w1b,
                        const float* __restrict__ w1c, _Float16* __restrict__ wf) {
    int c = blockIdx.x * blockDim.x + threadIdx.x;
    if (c >= NB * 8192) return;
    int b = c >> 13, r = c & 8191;
    const float* W; int t;
    if (r < 4096)      { W = w1a + (size_t)b * 2 * DH * DH; t = r >> 9; }
    else if (r < 6144) { W = w1b + (size_t)b * DH * DH;     t = (r - 4096) >> 9; }
    else               { W = w1c + (size_t)b * DH * DH;     t = (r - 6144) >> 9; }
    int n = (r >> 6) & 7, l = r & 63;
    int row0 = t * 32 + (l >> 4) * 8, col = n * 16 + (l & 15);
    half8 v;
#pragma unroll
    for (int j = 0; j < 8; ++j) v[j] = (_Float16)W[(size_t)(row0 + j) * DH + col];
    *(half8*)(wf + (size_t)c * 8) = v;
}

// ---------------------------------------------------------------------------
// CSR sort by dst: hist -> 3-phase scan -> scatter
__global__ void k_hist(const int* __restrict__ dstI, int* __restrict__ deg) {
    int e = blockIdx.x * blockDim.x + threadIdx.x;
    if (e < NE) atomicAdd(&deg[dstI[e]], 1);
}

__global__ void __launch_bounds__(1024) k_scanA(const int* __restrict__ deg,
                                                int* __restrict__ bsum) {
    __shared__ int ws[16];
    int tid = threadIdx.x, wv = tid >> 6, l = tid & 63;
    int i = blockIdx.x * 1024 + tid;
    int v = (i < NN) ? deg[i] : 0;
#pragma unroll
    for (int off = 32; off; off >>= 1) v += __shfl_down(v, off);
    if (l == 0) ws[wv] = v;
    __syncthreads();
    if (tid == 0) {
        int s = 0;
#pragma unroll
        for (int k = 0; k < 16; ++k) s += ws[k];
        bsum[blockIdx.x] = s;
    }
}

__global__ void k_scanB(const int* __restrict__ bsum, int* __restrict__ boff) {
    int l = threadIdx.x;  // 64 threads
    int v = (l < NBLK) ? bsum[l] : 0;
    int s = v;
#pragma unroll
    for (int off = 1; off < 64; off <<= 1) {
        int t = __shfl_up(s, off);
        if (l >= off) s += t;
    }
    if (l < NBLK) boff[l] = s - v;
}

__global__ void __launch_bounds__(1024) k_scanC(const int* __restrict__ deg,
                                                const int* __restrict__ boff,
                                                int* __restrict__ cur) {
    __shared__ int ws[16];
    int tid = threadIdx.x, wv = tid >> 6, l = tid & 63;
    int i = blockIdx.x * 1024 + tid;
    int v = (i < NN) ? deg[i] : 0;
    int s = v;
#pragma unroll
    for (int off = 1; off < 64; off <<= 1) {
        int t = __shfl_up(s, off);
        if (l >= off) s += t;
    }
    if (l == 63) ws[wv] = s;
    __syncthreads();
    if (wv == 0) {
        int t = (l < 16) ? ws[l] : 0;
#pragma unroll
        for (int off = 1; off < 16; off <<= 1) {
            int u = __shfl_up(t, off);
            if (l >= off) t += u;
        }
        if (l < 16) ws[l] = t;
    }
    __syncthreads();
    int base = boff[blockIdx.x] + (wv ? ws[wv - 1] : 0);
    if (i < NN) cur[i] = base + s - v;
}

__global__ void k_scatter(const int* __restrict__ srcI, const int* __restrict__ dstI,
                          int* __restrict__ cur, int* __restrict__ eS,
                          int* __restrict__ eD) {
    int e = blockIdx.x * blockDim.x + threadIdx.x;
    if (e >= NE) return;
    int d = dstI[e];
    int p = atomicAdd(&cur[d], 1);
    eS[p] = srcI[e];
    eD[p] = d;
}

// ---------------------------------------------------------------------------
// acc tile -> A-fragment-layout f16 in LDS (verified mapping, rounds 2-3)
__device__ __forceinline__ void ep_store(_Float16* sm, int off, const f32x4* acc,
                                         const float* bias, int lm, int lk,
                                         bool relu) {
#pragma unroll
    for (int n = 0; n < 8; ++n) {
        int base = off + (((n >> 1) * 64 + ((n & 1) * 2 + (lm >> 3)) * 16 + lk * 4) * 8)
                   + (lm & 7);
#pragma unroll
        for (int j = 0; j < 4; ++j) {
            float v = acc[n][j] + bias[n];
            if (relu) v = fmaxf(v, 0.f);
            sm[base + j * 8] = (_Float16)v;
        }
    }
}

// ---------------------------------------------------------------------------
// Edge MLP v4: independent waves, 64 dst-sorted edges per wave (quad-tile).
// 3 fused MFMA layers; epilogue = MFMA segment-sum over sorted-dst runs,
// then one atomicAdd per (distinct dst x feature). No __syncthreads.
__global__ void __launch_bounds__(256) k_edge4(
    const _Float16* __restrict__ xin,
    const int* __restrict__ eS, const int* __restrict__ eD,
    const half8* __restrict__ wfa, const half8* __restrict__ wfb,
    const half8* __restrict__ wfc,
    const float* __restrict__ b1a, const float* __restrict__ b1b,
    const float* __restrict__ b1c,
    float* __restrict__ agg) {
    __shared__ _Float16 sMall[4][8192];   // 16KB per wave
    __shared__ int dstSlotL[4][64];       // 2 halves x 32 slots per wave

    const int tid = threadIdx.x, wv = tid >> 6, l = tid & 63;
    const int lm = l & 15, lk = l >> 4;
    const long ebase = ((long)blockIdx.x * 4 + wv) * 64;
    if (ebase >= NE) return;

    _Float16* sm = sMall[wv];
    int* slotTab = dstSlotL[wv];

    // per-subtile A gather ids (lane lm -> edge row lm of subtile s)
    int srcs[4], dsts[4];
#pragma unroll
    for (int s = 0; s < 4; ++s) {
        int e = (int)ebase + s * 16 + lm;
        srcs[s] = eS[e];
        dsts[s] = eD[e];
    }

    // ---- run/slot machinery over the 64 sorted dsts (two independent 32-halves)
    int dl = eD[ebase + l];
    int prev = __shfl(dl, (l == 0) ? 0 : l - 1);
    bool bit = ((l & 31) == 0) ? true : (dl != prev);
    unsigned long long bal = __ballot(bit);
    unsigned mlo = (unsigned)bal, mhi = (unsigned)(bal >> 32);
    unsigned myM = (l < 32) ? mlo : mhi;
    int ll = l & 31;
    int slot_l = __popc(myM << (31 - ll)) - 1;   // rank of my run within half
    if (bit) slotTab[(l >> 5) * 32 + slot_l] = dl;
    int nlo = __popc(mlo), nhi = __popc(mhi);    // wave-uniform

    const f32x4 z = {0.f, 0.f, 0.f, 0.f};
    f32x4 acc[4][8];
#pragma unroll
    for (int s = 0; s < 4; ++s)
#pragma unroll
        for (int n = 0; n < 8; ++n) acc[s][n] = z;

    half8 aC[4], aN[4];

    // ---- layer 1: K=256 ([x_j | x_i]), weights streamed from L2
#pragma unroll
    for (int s = 0; s < 4; ++s)
        aC[s] = *(const half8*)(xin + (size_t)srcs[s] * DH + lk * 8);
    for (int t = 0; t < 8; ++t) {
        if (t < 7) {
            int t1 = t + 1;
#pragma unroll
            for (int s = 0; s < 4; ++s) {
                int node = (t1 < 4) ? srcs[s] : dsts[s];
                aN[s] = *(const half8*)(xin + (size_t)node * DH + (t1 & 3) * 32 + lk * 8);
            }
        }
        const half8* wp = wfa + (size_t)t * 512 + l;
#pragma unroll
        for (int n = 0; n < 8; ++n) {
            half8 w = wp[n * 64];
#pragma unroll
            for (int s = 0; s < 4; ++s)
                acc[s][n] = __builtin_amdgcn_mfma_f32_16x16x32_f16(aC[s], w, acc[s][n], 0, 0, 0);
        }
#pragma unroll
        for (int s = 0; s < 4; ++s) aC[s] = aN[s];
    }
    {
        float ba[8];
#pragma unroll
        for (int n = 0; n < 8; ++n) ba[n] = b1a[n * 16 + lm];
#pragma unroll
        for (int s = 0; s < 4; ++s) ep_store(sm, s * 2048, acc[s], ba, lm, lk, true);
    }
    FENCE();

    // ---- layer 2: K=128, A from LDS
#pragma unroll
    for (int s = 0; s < 4; ++s)
#pragma unroll
        for (int n = 0; n < 8; ++n) acc[s][n] = z;
    for (int t = 0; t < 4; ++t) {
#pragma unroll
        for (int s = 0; s < 4; ++s)
            aC[s] = *(const half8*)&sm[s * 2048 + (t * 64 + l) * 8];
        const half8* wp = wfb + (size_t)t * 512 + l;
#pragma unroll
        for (int n = 0; n < 8; ++n) {
            half8 w = wp[n * 64];
#pragma unroll
            for (int s = 0; s < 4; ++s)
                acc[s][n] = __builtin_amdgcn_mfma_f32_16x16x32_f16(aC[s], w, acc[s][n], 0, 0, 0);
        }
    }
    FENCE();   // all m1 reads done before overwrite
    {
        float bb[8];
#pragma unroll
        for (int n = 0; n < 8; ++n) bb[n] = b1b[n * 16 + lm];
#pragma unroll
        for (int s = 0; s < 4; ++s) ep_store(sm, s * 2048, acc[s], bb, lm, lk, true);
    }
    FENCE();

    // ---- layer 3: K=128
#pragma unroll
    for (int s = 0; s < 4; ++s)
#pragma unroll
        for (int n = 0; n < 8; ++n) acc[s][n] = z;
    for (int t = 0; t < 4; ++t) {
#pragma unroll
        for (int s = 0; s < 4; ++s)
            aC[s] = *(const half8*)&sm[s * 2048 + (t * 64 + l) * 8];
        const half8* wp = wfc + (size_t)t * 512 + l;
#pragma unroll
        for (int n = 0; n < 8; ++n) {
            half8 w = wp[n * 64];
#pragma unroll
            for (int s = 0; s < 4; ++s)
                acc[s][n] = __builtin_amdgcn_mfma_f32_16x16x32_f16(aC[s], w, acc[s][n], 0, 0, 0);
        }
    }
    FENCE();   // all m2 reads done before b-layout overwrite

    // ---- m3 (+bias) -> LDS in B-layout: lane l', chunk (g*64 + l'), elem e8
    //      holds m3[edge h*32 + (l'>>4)*8 + e8][g*16 + (l'&15)]
    {
        float bc[8];
#pragma unroll
        for (int n = 0; n < 8; ++n) bc[n] = b1c[n * 16 + lm];
#pragma unroll
        for (int s = 0; s < 4; ++s) {
            int h = s >> 1;
#pragma unroll
            for (int n = 0; n < 8; ++n) {
#pragma unroll
                for (int j = 0; j < 4; ++j) {
                    int e32 = (s * 16 + lk * 4 + j) & 31;
                    sm[h * 4096 + (n * 64 + (e32 >> 3) * 16 + lm) * 8 + (e32 & 7)] =
                        (_Float16)(acc[s][n][j] + bc[n]);
                }
            }
        }
    }
    FENCE();

    // ---- MFMA segment-sum + sparse atomic scatter, per 32-edge half
#pragma unroll
    for (int h = 0; h < 2; ++h) {
        const int nsl = h ? nhi : nlo;
        half8 ind0, ind1;
#pragma unroll
        for (int e8 = 0; e8 < 8; ++e8) {
            int se = __shfl(slot_l, h * 32 + lk * 8 + e8);
            ind0[e8] = (se == lm)      ? (_Float16)1.f : (_Float16)0.f;
            ind1[e8] = (se == lm + 16) ? (_Float16)1.f : (_Float16)0.f;
        }
        int dS[4], dS2[4];
#pragma unroll
        for (int r = 0; r < 4; ++r) {
            int s = lk * 4 + r;
            dS[r]  = (s < nsl && s < 16) ? slotTab[h * 32 + s] : -1;
            int s2 = 16 + s;
            dS2[r] = (s2 < nsl) ? slotTab[h * 32 + s2] : -1;
        }
#pragma unroll
        for (int g = 0; g < 8; ++g) {
            half8 b = *(const half8*)&sm[h * 4096 + (g * 64 + l) * 8];
            f32x4 p = __builtin_amdgcn_mfma_f32_16x16x32_f16(ind0, b, z, 0, 0, 0);
#pragma unroll
            for (int r = 0; r < 4; ++r)
                if (dS[r] >= 0)
                    unsafeAtomicAdd(agg + (size_t)dS[r] * DH + g * 16 + lm, p[r]);
            if (nsl > 16) {
                f32x4 p2 = __builtin_amdgcn_mfma_f32_16x16x32_f16(ind1, b, z, 0, 0, 0);
#pragma unroll
                for (int r = 0; r < 4; ++r)
                    if (dS2[r] >= 0)
                        unsafeAtomicAdd(agg + (size_t)dS2[r] * DH + g * 16 + lm, p2[r]);
            }
        }
    }
}

// ---------------------------------------------------------------------------
// fp32 tiled GEMM helper (known-correct, round 1/2)
template <int K, int LDA>
__device__ __forceinline__ void gemm_tile(const float* __restrict__ Wg,
                                          const float* sA_, float* sW,
                                          int tid, int eB, int hB,
                                          float acc[4][4]) {
    for (int kt = 0; kt < K; kt += 32) {
        __syncthreads();
#pragma unroll
        for (int i = 0; i < 4; ++i) {
            int row = (tid >> 5) + i * 8;
            int col = (tid & 31) * 4;
            *(float4*)&sW[row * 128 + col] =
                *(const float4*)(Wg + (size_t)(kt + row) * 128 + col);
        }
        __syncthreads();
#pragma unroll
        for (int kk = 0; kk < 32; kk += 4) {
            float4 a[4];
#pragma unroll
            for (int i = 0; i < 4; ++i)
                a[i] = *(const float4*)&sA_[(eB + i) * LDA + kt + kk];
#pragma unroll
            for (int q = 0; q < 4; ++q) {
                float4 w = *(const float4*)&sW[(kk + q) * 128 + hB];
#pragma unroll
                for (int i = 0; i < 4; ++i) {
                    float av = (&a[i].x)[q];
                    acc[i][0] = fmaf(av, w.x, acc[i][0]);
                    acc[i][1] = fmaf(av, w.y, acc[i][1]);
                    acc[i][2] = fmaf(av, w.z, acc[i][2]);
                    acc[i][3] = fmaf(av, w.w, acc[i][3]);
                }
            }
        }
    }
}

#define ZERO_ACC(acc)                          \
    _Pragma("unroll") for (int i_ = 0; i_ < 4; ++i_) \
        _Pragma("unroll") for (int j_ = 0; j_ < 4; ++j_) acc[i_][j_] = 0.f;

// ---------------------------------------------------------------------------
// Node MLP: xo = f16(relu(agg@w2a + b2a) @ w2b + b2b)   (known-correct)
__global__ void __launch_bounds__(256, 2) k_node(
    const float* __restrict__ agg,
    const float* __restrict__ w2a, const float* __restrict__ b2a,
    const float* __restrict__ w2b, const float* __restrict__ b2b,
    _Float16* __restrict__ xo) {
    __shared__ float sA[32 * 128];
    __shared__ float sB[32 * 128];
    __shared__ float sW[32 * 128];

    int tid = threadIdx.x;
    int n0 = blockIdx.x * 32;
    int lane4 = (tid & 31) * 4;
    int rgrp  = tid >> 5;
#pragma unroll
    for (int r = 0; r < 4; ++r) {
        int rr = r * 8 + rgrp;
        int n = n0 + rr;
        float4 v = make_float4(0.f, 0.f, 0.f, 0.f);
        if (n < NN) v = *(const float4*)(agg + (size_t)n * DH + lane4);
        *(float4*)&sA[rr * 128 + lane4] = v;
    }

    int eB = rgrp * 4;
    int hB = lane4;
    float acc[4][4];

    ZERO_ACC(acc);
    gemm_tile<128, 128>(w2a, sA, sW, tid, eB, hB, acc);
    {
        float4 b = *(const float4*)(b2a + hB);
#pragma unroll
        for (int i = 0; i < 4; ++i) {
            float4 v;
            v.x = fmaxf(acc[i][0] + b.x, 0.f);
            v.y = fmaxf(acc[i][1] + b.y, 0.f);
            v.z = fmaxf(acc[i][2] + b.z, 0.f);
            v.w = fmaxf(acc[i][3] + b.w, 0.f);
            *(float4*)&sB[(eB + i) * 128 + hB] = v;
        }
    }
    __syncthreads();

    ZERO_ACC(acc);
    gemm_tile<128, 128>(w2b, sB, sW, tid, eB, hB, acc);
    {
        float4 b = *(const float4*)(b2b + hB);
#pragma unroll
        for (int i = 0; i < 4; ++i) {
            int n = n0 + eB + i;
            if (n < NN) {
                _Float16 h0 = (_Float16)(acc[i][0] + b.x);
                _Float16 h1 = (_Float16)(acc[i][1] + b.y);
                _Float16 h2 = (_Float16)(acc[i][2] + b.z);
                _Float16 h3 = (_Float16)(acc[i][3] + b.w);
                _Float16* q = &xo[(size_t)n * DH + hB];
                q[0] = h0; q[1] = h1; q[2] = h2; q[3] = h3;
            }
        }
    }
}

// ---------------------------------------------------------------------------
__global__ void k_out(const _Float16* __restrict__ x16,
                      const float* __restrict__ wout,
                      const float* __restrict__ bout,
                      float* __restrict__ out) {
    int gid = blockIdx.x * blockDim.x + threadIdx.x;
    if (gid >= NN * DOUT) return;
    int n = gid >> 4, o = gid & 15;
    float acc = bout[o];
    const _Float16* row = x16 + (size_t)n * DH;
#pragma unroll 8
    for (int k = 0; k < DH; ++k) acc = fmaf((float)row[k], wout[k * DOUT + o], acc);
    out[gid] = acc;
}

// ---------------------------------------------------------------------------
extern "C" void kernel_launch(void* const* d_in, const int* in_sizes, int n_in,
                              void* d_out, int out_size, void* d_ws, size_t ws_size,
                              hipStream_t stream) {
    const float* inputs = (const float*)d_in[0];
    const int* eidx = (const int*)d_in[2];
    const int* srcI = eidx;
    const int* dstI = eidx + NE;
    const float* win  = (const float*)d_in[3];
    const float* bin_ = (const float*)d_in[4];
    const float* wout = (const float*)d_in[5];
    const float* bout = (const float*)d_in[6];
    const float* w1a = (const float*)d_in[7];
    const float* b1a = (const float*)d_in[8];
    const float* w1b = (const float*)d_in[9];
    const float* b1b = (const float*)d_in[10];
    const float* w1c = (const float*)d_in[11];
    const float* b1c = (const float*)d_in[12];
    const float* w2a = (const float*)d_in[13];
    const float* b2a = (const float*)d_in[14];
    const float* w2b = (const float*)d_in[15];
    const float* b2b = (const float*)d_in[16];

    char* p = (char*)d_ws;
    _Float16* xa = (_Float16*)p;    p += (size_t)NN * DH * 2;      // 12.8MB
    _Float16* xb = (_Float16*)p;    p += (size_t)NN * DH * 2;      // 12.8MB
    _Float16* wf = (_Float16*)p;    p += (size_t)NB * 8192 * 16;   // 256KB
    float* agg   = (float*)p;       p += (size_t)NN * DH * 4;      // 25.6MB
    int* deg     = (int*)p;         p += (size_t)NN * 4;
    int* cur     = (int*)p;         p += (size_t)NN * 4;
    int* bsum    = (int*)p;         p += 256;
    int* boff    = (int*)p;         p += 256;
    int* eSrt    = (int*)p;         p += (size_t)NE * 4;
    int* eDrt    = (int*)p;         p += (size_t)NE * 4;
    float* out   = (float*)d_out;

    k_wprep<<<(NB * 8192 + 255) / 256, 256, 0, stream>>>(w1a, w1b, w1c, wf);
    k_node_proj<<<(NN * DH + 255) / 256, 256, 0, stream>>>(inputs, win, bin_, xa);

    hipMemsetAsync(deg, 0, (size_t)NN * 4, stream);
    k_hist<<<(NE + 255) / 256, 256, 0, stream>>>(dstI, deg);
    k_scanA<<<NBLK, 1024, 0, stream>>>(deg, bsum);
    k_scanB<<<1, 64, 0, stream>>>(bsum, boff);
    k_scanC<<<NBLK, 1024, 0, stream>>>(deg, boff, cur);
    k_scatter<<<(NE + 255) / 256, 256, 0, stream>>>(srcI, dstI, cur, eSrt, eDrt);

    const int NWG_E = (NE / 64 + 3) / 4;   // 4 waves/wg, 64 edges/wave
    for (int b = 0; b < NB; ++b) {
        const _Float16* xi = (b & 1) ? xb : xa;
        _Float16*       xo = (b & 1) ? xa : xb;
        hipMemsetAsync(agg, 0, (size_t)NN * DH * 4, stream);
        const half8* wfa = (const half8*)(wf + (size_t)b * 8192 * 8);
        k_edge4<<<NWG_E, 256, 0, stream>>>(
            xi, eSrt, eDrt, wfa, wfa + 4096, wfa + 6144,
            b1a + (size_t)b * DH, b1b + (size_t)b * DH, b1c + (size_t)b * DH,
            agg);
        k_node<<<(NN + 31) / 32, 256, 0, stream>>>(
            agg,
            w2a + (size_t)b * DH * DH, b2a + (size_t)b * DH,
            w2b + (size_t)b * DH * DH, b2b + (size_t)b * DH,
            xo);
    }

    k_out<<<(NN * DOUT + 255) / 256, 256, 0, stream>>>(xa, wout, bout, out);
}

// Round 5
// 397.483 us; speedup vs baseline: 2.3463x; 1.6650x over previous
//
#include <hip/hip_runtime.h>

#define NN 50000
#define NE 400000
#define DIN 32
#define DH  128
#define DOUT 16
#define NB  2
#define NBLK 49   // ceil(NN/1024)

typedef _Float16 half8 __attribute__((ext_vector_type(8)));
typedef float    f32x4 __attribute__((ext_vector_type(4)));

#define FENCE() asm volatile("s_waitcnt lgkmcnt(0)" ::: "memory")
#define MFMA16(a, b, c) __builtin_amdgcn_mfma_f32_16x16x32_f16((a), (b), (c), 0, 0, 0)

// ---------------------------------------------------------------------------
__global__ void k_node_proj(const float* __restrict__ inp,
                            const float* __restrict__ win,
                            const float* __restrict__ bin,
                            _Float16* __restrict__ x16) {
    int gid = blockIdx.x * blockDim.x + threadIdx.x;
    if (gid >= NN * DH) return;
    int n = gid >> 7, h = gid & 127;
    float acc = bin[h];
    const float* row = inp + (size_t)n * DIN;
#pragma unroll
    for (int k = 0; k < DIN; ++k) acc = fmaf(row[k], win[k * DH + h], acc);
    x16[gid] = (_Float16)acc;
}

// ---------------------------------------------------------------------------
// Fragment-linear f16 weights (verified rounds 2-3). Per block, 24 t-tiles
// x 512 chunks of 8 f16: w1a(t0..7) w1b(4) w1c(4) w2a(4) w2b(4).
// chunk within matrix = (t*8+n)*64+l; elem j = W[t*32+(l>>4)*8+j][n*16+(l&15)]
__global__ void k_wprep(const float* __restrict__ w1a, const float* __restrict__ w1b,
                        const float* __restrict__ w1c, const float* __restrict__ w2a,
                        const float* __restrict__ w2b, _Float16* __restrict__ wf) {
    int c = blockIdx.x * blockDim.x + threadIdx.x;
    if (c >= NB * 12288) return;
    int b = c / 12288, r = c % 12288;
    int tt = r >> 9, rem = r & 511;
    const float* W; int t;
    if (tt < 8)       { W = w1a + (size_t)b * 2 * DH * DH; t = tt; }
    else if (tt < 12) { W = w1b + (size_t)b * DH * DH; t = tt - 8; }
    else if (tt < 16) { W = w1c + (size_t)b * DH * DH; t = tt - 12; }
    else if (tt < 20) { W = w2a + (size_t)b * DH * DH; t = tt - 16; }
    else              { W = w2b + (size_t)b * DH * DH; t = tt - 20; }
    int n = rem >> 6, l = rem & 63;
    int row0 = t * 32 + (l >> 4) * 8, col = n * 16 + (l & 15);
    half8 v;
#pragma unroll
    for (int j = 0; j < 8; ++j) v[j] = (_Float16)W[(size_t)(row0 + j) * DH + col];
    *(half8*)(wf + (size_t)c * 8) = v;
}

// ---------------------------------------------------------------------------
// CSR sort by dst: hist -> 3-phase scan -> scatter
__global__ void k_hist(const int* __restrict__ dstI, int* __restrict__ deg) {
    int e = blockIdx.x * blockDim.x + threadIdx.x;
    if (e < NE) atomicAdd(&deg[dstI[e]], 1);
}

__global__ void __launch_bounds__(1024) k_scanA(const int* __restrict__ deg,
                                                int* __restrict__ bsum) {
    __shared__ int ws[16];
    int tid = threadIdx.x, wv = tid >> 6, l = tid & 63;
    int i = blockIdx.x * 1024 + tid;
    int v = (i < NN) ? deg[i] : 0;
#pragma unroll
    for (int off = 32; off; off >>= 1) v += __shfl_down(v, off);
    if (l == 0) ws[wv] = v;
    __syncthreads();
    if (tid == 0) {
        int s = 0;
#pragma unroll
        for (int k = 0; k < 16; ++k) s += ws[k];
        bsum[blockIdx.x] = s;
    }
}

__global__ void k_scanB(const int* __restrict__ bsum, int* __restrict__ boff) {
    int l = threadIdx.x;  // 64 threads
    int v = (l < NBLK) ? bsum[l] : 0;
    int s = v;
#pragma unroll
    for (int off = 1; off < 64; off <<= 1) {
        int t = __shfl_up(s, off);
        if (l >= off) s += t;
    }
    if (l < NBLK) boff[l] = s - v;
}

__global__ void __launch_bounds__(1024) k_scanC(const int* __restrict__ deg,
                                                const int* __restrict__ boff,
                                                int* __restrict__ cur) {
    __shared__ int ws[16];
    int tid = threadIdx.x, wv = tid >> 6, l = tid & 63;
    int i = blockIdx.x * 1024 + tid;
    int v = (i < NN) ? deg[i] : 0;
    int s = v;
#pragma unroll
    for (int off = 1; off < 64; off <<= 1) {
        int t = __shfl_up(s, off);
        if (l >= off) s += t;
    }
    if (l == 63) ws[wv] = s;
    __syncthreads();
    if (wv == 0) {
        int t = (l < 16) ? ws[l] : 0;
#pragma unroll
        for (int off = 1; off < 16; off <<= 1) {
            int u = __shfl_up(t, off);
            if (l >= off) t += u;
        }
        if (l < 16) ws[l] = t;
    }
    __syncthreads();
    int base = boff[blockIdx.x] + (wv ? ws[wv - 1] : 0);
    if (i < NN) cur[i] = base + s - v;
}

__global__ void k_scatter(const int* __restrict__ srcI, const int* __restrict__ dstI,
                          int* __restrict__ cur, int* __restrict__ eS,
                          int* __restrict__ eD) {
    int e = blockIdx.x * blockDim.x + threadIdx.x;
    if (e >= NE) return;
    int d = dstI[e];
    int p = atomicAdd(&cur[d], 1);
    eS[p] = srcI[e];
    eD[p] = d;
}

// ---------------------------------------------------------------------------
// Edge MLP v5: one 64-edge dst-sorted tile per wg; 4 waves split the 8
// feature groups (2 each). acc=32 regs/wave, shared 16KB m-buffer, 4
// barriers/tile. Weights double-buffered in regs from L2 (frag-linear).
// Epilogue: MFMA segment-sum over sorted-dst runs + sparse atomics.
__global__ void __launch_bounds__(256, 4) k_edge5(
    const _Float16* __restrict__ xin,
    const int* __restrict__ eS, const int* __restrict__ eD,
    const half8* __restrict__ wfa, const half8* __restrict__ wfb,
    const half8* __restrict__ wfc,
    const float* __restrict__ b1a, const float* __restrict__ b1b,
    const float* __restrict__ b1c,
    float* __restrict__ agg) {
    __shared__ _Float16 sm[8192];     // 16KB: 64 edges x 128 feats (A-frag layout)
    __shared__ int slotT[4][64];

    const int tid = threadIdx.x, wv = tid >> 6, l = tid & 63;
    const int lm = l & 15, lk = l >> 4;
    const int nb = wv * 2;                    // this wave's feature groups
    const int ebase = blockIdx.x * 64;

    int srcs[4], dsts[4];
#pragma unroll
    for (int s = 0; s < 4; ++s) {
        srcs[s] = eS[ebase + s * 16 + lm];
        dsts[s] = eD[ebase + s * 16 + lm];
    }

    // run/slot machinery over 64 sorted dsts (two 32-halves), per wave
    int dl = eD[ebase + l];
    int prev = __shfl(dl, (l == 0) ? 0 : l - 1);
    bool bit = ((l & 31) == 0) ? true : (dl != prev);
    unsigned long long bal = __ballot(bit);
    unsigned mlo = (unsigned)bal, mhi = (unsigned)(bal >> 32);
    unsigned myM = (l < 32) ? mlo : mhi;
    int ll = l & 31;
    int slot_l = __popc(myM << (31 - ll)) - 1;
    if (bit) slotT[wv][(l >> 5) * 32 + slot_l] = dl;
    int nlo = __popc(mlo), nhi = __popc(mhi);

    float ba[2], bb[2], bc[2];
#pragma unroll
    for (int q = 0; q < 2; ++q) {
        ba[q] = b1a[(nb + q) * 16 + lm];
        bb[q] = b1b[(nb + q) * 16 + lm];
        bc[q] = b1c[(nb + q) * 16 + lm];
    }

    const f32x4 z = {0.f, 0.f, 0.f, 0.f};
    f32x4 acc[4][2];
    half8 aC[4], aN[4], wC[2], wN[2];

    // ---- layer 1: K=256 ([x_j | x_i])
#pragma unroll
    for (int s = 0; s < 4; ++s)
#pragma unroll
        for (int q = 0; q < 2; ++q) acc[s][q] = z;
#pragma unroll
    for (int s = 0; s < 4; ++s)
        aC[s] = *(const half8*)(xin + (size_t)srcs[s] * DH + lk * 8);
#pragma unroll
    for (int q = 0; q < 2; ++q) wC[q] = wfa[(size_t)(nb + q) * 64 + l];

    for (int t = 0; t < 8; ++t) {
        if (t < 7) {
            int t1 = t + 1;
#pragma unroll
            for (int s = 0; s < 4; ++s) {
                int node = (t1 < 4) ? srcs[s] : dsts[s];
                aN[s] = *(const half8*)(xin + (size_t)node * DH + (t1 & 3) * 32 + lk * 8);
            }
#pragma unroll
            for (int q = 0; q < 2; ++q)
                wN[q] = wfa[(size_t)(t1 * 8 + nb + q) * 64 + l];
        }
#pragma unroll
        for (int q = 0; q < 2; ++q)
#pragma unroll
            for (int s = 0; s < 4; ++s)
                acc[s][q] = MFMA16(aC[s], wC[q], acc[s][q]);
#pragma unroll
        for (int s = 0; s < 4; ++s) aC[s] = aN[s];
#pragma unroll
        for (int q = 0; q < 2; ++q) wC[q] = wN[q];
    }
    // ep1: bias+relu -> m1 (this wave's feature quarter of each subtile region)
#pragma unroll
    for (int s = 0; s < 4; ++s)
#pragma unroll
        for (int q = 0; q < 2; ++q) {
            int n = nb + q;
            int base = s * 2048 +
                       ((n >> 1) * 64 + ((n & 1) * 2 + (lm >> 3)) * 16 + lk * 4) * 8 +
                       (lm & 7);
#pragma unroll
            for (int j = 0; j < 4; ++j)
                sm[base + j * 8] = (_Float16)fmaxf(acc[s][q][j] + ba[q], 0.f);
        }
    __syncthreads();   // m1 complete (all waves)

    // ---- layer 2: K=128
#pragma unroll
    for (int s = 0; s < 4; ++s)
#pragma unroll
        for (int q = 0; q < 2; ++q) acc[s][q] = z;
#pragma unroll
    for (int q = 0; q < 2; ++q) wC[q] = wfb[(size_t)(nb + q) * 64 + l];
    for (int t = 0; t < 4; ++t) {
        if (t < 3)
#pragma unroll
            for (int q = 0; q < 2; ++q)
                wN[q] = wfb[(size_t)((t + 1) * 8 + nb + q) * 64 + l];
#pragma unroll
        for (int s = 0; s < 4; ++s)
            aC[s] = *(const half8*)&sm[s * 2048 + (t * 64 + l) * 8];
#pragma unroll
        for (int q = 0; q < 2; ++q)
#pragma unroll
            for (int s = 0; s < 4; ++s)
                acc[s][q] = MFMA16(aC[s], wC[q], acc[s][q]);
#pragma unroll
        for (int q = 0; q < 2; ++q) wC[q] = wN[q];
    }
    __syncthreads();   // all m1 reads done before in-place overwrite
#pragma unroll
    for (int s = 0; s < 4; ++s)
#pragma unroll
        for (int q = 0; q < 2; ++q) {
            int n = nb + q;
            int base = s * 2048 +
                       ((n >> 1) * 64 + ((n & 1) * 2 + (lm >> 3)) * 16 + lk * 4) * 8 +
                       (lm & 7);
#pragma unroll
            for (int j = 0; j < 4; ++j)
                sm[base + j * 8] = (_Float16)fmaxf(acc[s][q][j] + bb[q], 0.f);
        }
    __syncthreads();   // m2 complete

    // ---- layer 3: K=128
#pragma unroll
    for (int s = 0; s < 4; ++s)
#pragma unroll
        for (int q = 0; q < 2; ++q) acc[s][q] = z;
#pragma unroll
    for (int q = 0; q < 2; ++q) wC[q] = wfc[(size_t)(nb + q) * 64 + l];
    for (int t = 0; t < 4; ++t) {
        if (t < 3)
#pragma unroll
            for (int q = 0; q < 2; ++q)
                wN[q] = wfc[(size_t)((t + 1) * 8 + nb + q) * 64 + l];
#pragma unroll
        for (int s = 0; s < 4; ++s)
            aC[s] = *(const half8*)&sm[s * 2048 + (t * 64 + l) * 8];
#pragma unroll
        for (int q = 0; q < 2; ++q)
#pragma unroll
            for (int s = 0; s < 4; ++s)
                acc[s][q] = MFMA16(aC[s], wC[q], acc[s][q]);
#pragma unroll
        for (int q = 0; q < 2; ++q) wC[q] = wN[q];
    }
    __syncthreads();   // all m2 reads done before b-layout overwrite

    // ---- m3+bias -> B-layout (per-wave-private chunks h*512 + n*64 + ...)
#pragma unroll
    for (int s = 0; s < 4; ++s) {
        int h = s >> 1;
#pragma unroll
        for (int q = 0; q < 2; ++q) {
            int n = nb + q;
#pragma unroll
            for (int j = 0; j < 4; ++j) {
                int e32 = (s * 16 + lk * 4 + j) & 31;
                sm[h * 4096 + (n * 64 + (e32 >> 3) * 16 + lm) * 8 + (e32 & 7)] =
                    (_Float16)(acc[s][q][j] + bc[q]);
            }
        }
    }
    FENCE();

    // ---- MFMA segment-sum + sparse atomic scatter, per 32-edge half
#pragma unroll
    for (int h = 0; h < 2; ++h) {
        const int nsl = h ? nhi : nlo;
        half8 ind0, ind1;
#pragma unroll
        for (int e8 = 0; e8 < 8; ++e8) {
            int se = __shfl(slot_l, h * 32 + lk * 8 + e8);
            ind0[e8] = (se == lm)      ? (_Float16)1.f : (_Float16)0.f;
            ind1[e8] = (se == lm + 16) ? (_Float16)1.f : (_Float16)0.f;
        }
        int dS[4], dS2[4];
#pragma unroll
        for (int r = 0; r < 4; ++r) {
            int s = lk * 4 + r;
            dS[r]  = (s < nsl && s < 16) ? slotT[wv][h * 32 + s] : -1;
            int s2 = 16 + s;
            dS2[r] = (s2 < nsl) ? slotT[wv][h * 32 + s2] : -1;
        }
#pragma unroll
        for (int q = 0; q < 2; ++q) {
            int g = nb + q;
            half8 bfrag = *(const half8*)&sm[(h * 512 + g * 64 + l) * 8];
            f32x4 p = MFMA16(ind0, bfrag, z);
#pragma unroll
            for (int r = 0; r < 4; ++r)
                if (dS[r] >= 0)
                    unsafeAtomicAdd(agg + (size_t)dS[r] * DH + g * 16 + lm, p[r]);
            if (nsl > 16) {
                f32x4 p2 = MFMA16(ind1, bfrag, z);
#pragma unroll
                for (int r = 0; r < 4; ++r)
                    if (dS2[r] >= 0)
                        unsafeAtomicAdd(agg + (size_t)dS2[r] * DH + g * 16 + lm, p2[r]);
            }
        }
    }
}

// ---------------------------------------------------------------------------
// Node MLP via MFMA: xo = f16(relu(agg@w2a+b2a)@w2b+b2b). 16 nodes/wave,
// independent waves (no barriers), per-wave 4KB LDS frag buffer.
__global__ void __launch_bounds__(256) k_node_mfma(
    const float* __restrict__ agg,
    const half8* __restrict__ wfa, const half8* __restrict__ wfb,
    const float* __restrict__ b2a, const float* __restrict__ b2b,
    _Float16* __restrict__ xo) {
    __shared__ _Float16 sM[4][2048];
    const int tid = threadIdx.x, wv = tid >> 6, l = tid & 63;
    const int lm = l & 15, lk = l >> 4;
    const int n0 = (blockIdx.x * 4 + wv) * 16;
    if (n0 >= NN) return;   // whole-wave OOB; no barriers in this kernel
    int nodeA = n0 + lm;
    if (nodeA >= NN) nodeA = NN - 1;

    float b2ar[8], b2br[8];
#pragma unroll
    for (int n = 0; n < 8; ++n) {
        b2ar[n] = b2a[n * 16 + lm];
        b2br[n] = b2b[n * 16 + lm];
    }

    const f32x4 z = {0.f, 0.f, 0.f, 0.f};
    f32x4 acc[8];
#pragma unroll
    for (int n = 0; n < 8; ++n) acc[n] = z;

    for (int t = 0; t < 4; ++t) {
        const float* ap = agg + (size_t)nodeA * DH + t * 32 + lk * 8;
        float4 v0 = *(const float4*)ap;
        float4 v1 = *(const float4*)(ap + 4);
        half8 a;
        a[0] = (_Float16)v0.x; a[1] = (_Float16)v0.y;
        a[2] = (_Float16)v0.z; a[3] = (_Float16)v0.w;
        a[4] = (_Float16)v1.x; a[5] = (_Float16)v1.y;
        a[6] = (_Float16)v1.z; a[7] = (_Float16)v1.w;
        const half8* wp = wfa + (size_t)t * 512 + l;
#pragma unroll
        for (int n = 0; n < 8; ++n) acc[n] = MFMA16(a, wp[n * 64], acc[n]);
    }
    _Float16* sm = sM[wv];
#pragma unroll
    for (int n = 0; n < 8; ++n) {
        int base = ((n >> 1) * 64 + ((n & 1) * 2 + (lm >> 3)) * 16 + lk * 4) * 8 +
                   (lm & 7);
#pragma unroll
        for (int j = 0; j < 4; ++j)
            sm[base + j * 8] = (_Float16)fmaxf(acc[n][j] + b2ar[n], 0.f);
    }
    FENCE();
#pragma unroll
    for (int n = 0; n < 8; ++n) acc[n] = z;
    for (int t = 0; t < 4; ++t) {
        half8 a = *(const half8*)&sm[(t * 64 + l) * 8];
        const half8* wp = wfb + (size_t)t * 512 + l;
#pragma unroll
        for (int n = 0; n < 8; ++n) acc[n] = MFMA16(a, wp[n * 64], acc[n]);
    }
#pragma unroll
    for (int n = 0; n < 8; ++n) {
#pragma unroll
        for (int j = 0; j < 4; ++j) {
            int nd = n0 + lk * 4 + j;
            if (nd < NN)
                xo[(size_t)nd * DH + n * 16 + lm] = (_Float16)(acc[n][j] + b2br[n]);
        }
    }
}

// ---------------------------------------------------------------------------
__global__ void k_out(const _Float16* __restrict__ x16,
                      const float* __restrict__ wout,
                      const float* __restrict__ bout,
                      float* __restrict__ out) {
    int gid = blockIdx.x * blockDim.x + threadIdx.x;
    if (gid >= NN * DOUT) return;
    int n = gid >> 4, o = gid & 15;
    float acc = bout[o];
    const _Float16* row = x16 + (size_t)n * DH;
#pragma unroll 8
    for (int k = 0; k < DH; ++k) acc = fmaf((float)row[k], wout[k * DOUT + o], acc);
    out[gid] = acc;
}

// ---------------------------------------------------------------------------
extern "C" void kernel_launch(void* const* d_in, const int* in_sizes, int n_in,
                              void* d_out, int out_size, void* d_ws, size_t ws_size,
                              hipStream_t stream) {
    const float* inputs = (const float*)d_in[0];
    const int* eidx = (const int*)d_in[2];
    const int* srcI = eidx;
    const int* dstI = eidx + NE;
    const float* win  = (const float*)d_in[3];
    const float* bin_ = (const float*)d_in[4];
    const float* wout = (const float*)d_in[5];
    const float* bout = (const float*)d_in[6];
    const float* w1a = (const float*)d_in[7];
    const float* b1a = (const float*)d_in[8];
    const float* w1b = (const float*)d_in[9];
    const float* b1b = (const float*)d_in[10];
    const float* w1c = (const float*)d_in[11];
    const float* b1c = (const float*)d_in[12];
    const float* w2a = (const float*)d_in[13];
    const float* b2a = (const float*)d_in[14];
    const float* w2b = (const float*)d_in[15];
    const float* b2b = (const float*)d_in[16];

    char* p = (char*)d_ws;
    _Float16* xa = (_Float16*)p;    p += (size_t)NN * DH * 2;       // 12.8MB
    _Float16* xb = (_Float16*)p;    p += (size_t)NN * DH * 2;       // 12.8MB
    _Float16* wfAll = (_Float16*)p; p += (size_t)NB * 12288 * 16;   // 393KB
    float* agg   = (float*)p;       p += (size_t)NN * DH * 4;       // 25.6MB
    int* deg     = (int*)p;         p += (size_t)NN * 4;
    int* cur     = (int*)p;         p += (size_t)NN * 4;
    int* bsum    = (int*)p;         p += 256;
    int* boff    = (int*)p;         p += 256;
    int* eSrt    = (int*)p;         p += (size_t)NE * 4;
    int* eDrt    = (int*)p;         p += (size_t)NE * 4;
    float* out   = (float*)d_out;

    k_wprep<<<(NB * 12288 + 255) / 256, 256, 0, stream>>>(w1a, w1b, w1c, w2a, w2b, wfAll);
    k_node_proj<<<(NN * DH + 255) / 256, 256, 0, stream>>>(inputs, win, bin_, xa);

    hipMemsetAsync(deg, 0, (size_t)NN * 4, stream);
    k_hist<<<(NE + 255) / 256, 256, 0, stream>>>(dstI, deg);
    k_scanA<<<NBLK, 1024, 0, stream>>>(deg, bsum);
    k_scanB<<<1, 64, 0, stream>>>(bsum, boff);
    k_scanC<<<NBLK, 1024, 0, stream>>>(deg, boff, cur);
    k_scatter<<<(NE + 255) / 256, 256, 0, stream>>>(srcI, dstI, cur, eSrt, eDrt);

    for (int b = 0; b < NB; ++b) {
        const _Float16* xi = (b & 1) ? xb : xa;
        _Float16*       xo = (b & 1) ? xa : xb;
        hipMemsetAsync(agg, 0, (size_t)NN * DH * 4, stream);
        const half8* whalf = (const half8*)(wfAll + (size_t)b * 12288 * 8);
        k_edge5<<<NE / 64, 256, 0, stream>>>(
            xi, eSrt, eDrt, whalf, whalf + 4096, whalf + 6144,
            b1a + (size_t)b * DH, b1b + (size_t)b * DH, b1c + (size_t)b * DH,
            agg);
        k_node_mfma<<<(NN + 63) / 64, 256, 0, stream>>>(
            agg, whalf + 8192, whalf + 10240,
            b2a + (size_t)b * DH, b2b + (size_t)b * DH,
            xo);
    }

    k_out<<<(NN * DOUT + 255) / 256, 256, 0, stream>>>(xa, wout, bout, out);
}